// Round 1
// baseline (253.016 us; speedup 1.0000x reference)
//
#include <hip/hip_runtime.h>

#define TPB 256
#define SUBTILE 512
#define CHUNKS 4

// Seed min arrays to +inf bits (workspace is poisoned 0xAA before each launch).
__global__ void cham_init_kernel(unsigned int* __restrict__ mins, int count) {
    int i = blockIdx.x * blockDim.x + threadIdx.x;
    if (i < count) mins[i] = 0x7F800000u;  // +inf
}

// side 0 blocks: own = fg rows (N of them), other = prj (M), out = rowmin
// side 1 blocks: own = prj points (M),     other = fg (N),  out = colmin
__global__ __launch_bounds__(TPB) void cham_dist_kernel(
    const float* __restrict__ fg, const float* __restrict__ prj,
    unsigned int* __restrict__ rowmin, unsigned int* __restrict__ colmin,
    int B, int N, int M, int tilesX, int tilesY)
{
    const int blocksX = B * tilesX * CHUNKS;
    int idx = blockIdx.x;
    const int side = (idx >= blocksX) ? 1 : 0;
    if (side) idx -= blocksX;
    const int tilesPer = side ? tilesY : tilesX;
    const int b     = idx / (tilesPer * CHUNKS);
    const int rem   = idx % (tilesPer * CHUNKS);
    const int tile  = rem / CHUNKS;
    const int chunk = rem % CHUNKS;

    const float* own        = side ? prj : fg;
    const float* other      = side ? fg  : prj;
    unsigned int* outArr    = side ? colmin : rowmin;
    const int ownCount      = side ? M : N;
    const int otherCount    = side ? N : M;

    const int i = tile * TPB + threadIdx.x;  // my point index
    const bool alive = (i < ownCount);
    float ax = 0.f, ay = 0.f, az = 0.f;
    if (alive) {
        const float* p = own + ((size_t)b * ownCount + i) * 3;
        ax = p[0]; ay = p[1]; az = p[2];
    }

    const int chunkLen = (otherCount + CHUNKS - 1) / CHUNKS;
    const int start = chunk * chunkLen;
    const int end   = min(start + chunkLen, otherCount);

    __shared__ float4 tilebuf[SUBTILE];
    float mn = __int_as_float(0x7F800000);  // +inf

    for (int t0 = start; t0 < end; t0 += SUBTILE) {
        const int cnt = min(SUBTILE, end - t0);
        __syncthreads();
        for (int j = threadIdx.x; j < cnt; j += TPB) {
            const float* q = other + ((size_t)b * otherCount + t0 + j) * 3;
            tilebuf[j] = make_float4(q[0], q[1], q[2], 0.f);
        }
        __syncthreads();
        #pragma unroll 8
        for (int j = 0; j < cnt; ++j) {
            float4 p = tilebuf[j];
            float dx = ax - p.x, dy = ay - p.y, dz = az - p.z;
            float d2 = dx * dx + dy * dy + dz * dz;  // >= 0 always (direct form)
            mn = fminf(mn, d2);
        }
    }
    // nonnegative float bit pattern order == unsigned order
    if (alive) atomicMin(&outArr[(size_t)b * ownCount + i], __float_as_uint(mn));
}

// One block folds everything: sum(rowmin[n<L])/L + sum(colmin)/M per batch, /B.
__global__ __launch_bounds__(256) void cham_reduce_kernel(
    const unsigned int* __restrict__ rowmin, const unsigned int* __restrict__ colmin,
    const int* __restrict__ lengths, float* __restrict__ out, int B, int N, int M)
{
    __shared__ float wavesum[4];
    const int tid  = threadIdx.x;
    const int lane = tid & 63;
    const int wave = tid >> 6;
    float total = 0.f;

    for (int b = 0; b < B; ++b) {
        const int L = lengths[b];
        float sx = 0.f, sy = 0.f;
        for (int n = tid; n < L; n += 256) sx += __uint_as_float(rowmin[(size_t)b * N + n]);
        for (int m = tid; m < M; m += 256) sy += __uint_as_float(colmin[(size_t)b * M + m]);
        float v = sx / (float)L + sy / (float)M;
        #pragma unroll
        for (int off = 32; off > 0; off >>= 1) v += __shfl_down(v, off, 64);
        if (lane == 0) wavesum[wave] = v;
        __syncthreads();
        if (tid == 0) {
            total += wavesum[0] + wavesum[1] + wavesum[2] + wavesum[3];
        }
        __syncthreads();
    }
    if (tid == 0) out[0] = total / (float)B;
}

extern "C" void kernel_launch(void* const* d_in, const int* in_sizes, int n_in,
                              void* d_out, int out_size, void* d_ws, size_t ws_size,
                              hipStream_t stream) {
    const float* fg      = (const float*)d_in[0];
    const float* prj     = (const float*)d_in[1];
    const int*   lengths = (const int*)d_in[2];
    float*       out     = (float*)d_out;

    const int B = in_sizes[2];
    const int N = in_sizes[0] / (3 * B);
    const int M = in_sizes[1] / (3 * B);

    unsigned int* rowmin = (unsigned int*)d_ws;
    unsigned int* colmin = rowmin + (size_t)B * N;

    const int totalMins = B * (N + M);
    cham_init_kernel<<<(totalMins + 255) / 256, 256, 0, stream>>>(rowmin, totalMins);

    const int tilesX = (N + TPB - 1) / TPB;
    const int tilesY = (M + TPB - 1) / TPB;
    const int totalBlocks = B * (tilesX + tilesY) * CHUNKS;
    cham_dist_kernel<<<totalBlocks, TPB, 0, stream>>>(
        fg, prj, rowmin, colmin, B, N, M, tilesX, tilesY);

    cham_reduce_kernel<<<1, 256, 0, stream>>>(rowmin, colmin, lengths, out, B, N, M);
}

// Round 2
// 86.935 us; speedup vs baseline: 2.9104x; 2.9104x over previous
//
#include <hip/hip_runtime.h>

#define TPB 256
#define PPT 8                    // own points per thread
#define OWN_TILE (TPB * PPT)     // 2048 own points per block
#define CHUNK 128                // other points per block (staged once, 2KB LDS)

// Seed min arrays to +inf bits and zero the output accumulator
// (workspace/out are poisoned 0xAA before each timed launch).
__global__ void cham_init_kernel(unsigned int* __restrict__ mins, int count,
                                 float* __restrict__ out) {
    int i = blockIdx.x * blockDim.x + threadIdx.x;
    if (i < count) mins[i] = 0x7F800000u;  // +inf
    if (i == 0) out[0] = 0.f;
}

// side 0 blocks: own = fg rows (N), other = prj (M), out = rowmin
// side 1 blocks: own = prj (M),     other = fg (N),  out = colmin
// d2 = |a|^2 + (|b|^2 - 2 a.b); min over j of the paren term, add |a|^2, clamp 0.
__global__ __launch_bounds__(TPB) void cham_dist_kernel(
    const float* __restrict__ fg, const float* __restrict__ prj,
    unsigned int* __restrict__ rowmin, unsigned int* __restrict__ colmin,
    int B, int N, int M,
    int tilesX, int chunksX, int tilesY, int chunksY)
{
    const int blocksX = B * tilesX * chunksX;
    int idx = blockIdx.x;
    const int side = (idx >= blocksX) ? 1 : 0;
    if (side) idx -= blocksX;
    const int tilesPer  = side ? tilesY  : tilesX;
    const int chunksPer = side ? chunksY : chunksX;
    const int b     = idx / (tilesPer * chunksPer);
    const int rem   = idx % (tilesPer * chunksPer);
    const int tile  = rem / chunksPer;
    const int chunk = rem % chunksPer;

    const float* own     = side ? prj : fg;
    const float* other   = side ? fg  : prj;
    unsigned int* outArr = side ? colmin : rowmin;
    const int ownCount   = side ? M : N;
    const int otherCount = side ? N : M;

    // ---- load my PPT own points; precompute -2a and |a|^2 ----
    const int base = tile * OWN_TILE;
    float m2x[PPT], m2y[PPT], m2z[PPT], aa[PPT], mn[PPT];
    #pragma unroll
    for (int p = 0; p < PPT; ++p) {
        int i = base + p * TPB + threadIdx.x;
        int li = (i < ownCount) ? i : (ownCount - 1);  // clamped load, store guarded later
        const float* a = own + ((size_t)b * ownCount + li) * 3;
        float ax = a[0], ay = a[1], az = a[2];
        m2x[p] = -2.f * ax; m2y[p] = -2.f * ay; m2z[p] = -2.f * az;
        aa[p]  = ax * ax + ay * ay + az * az;
        mn[p]  = __int_as_float(0x7F800000);
    }

    // ---- stage my chunk of the other set into LDS (w = |b|^2) ----
    const int start = chunk * CHUNK;
    const int cnt   = min(CHUNK, otherCount - start);
    __shared__ float4 tilebuf[CHUNK];
    if (threadIdx.x < cnt) {
        const float* q = other + ((size_t)b * otherCount + start + threadIdx.x) * 3;
        float bx = q[0], by = q[1], bz = q[2];
        tilebuf[threadIdx.x] = make_float4(bx, by, bz, bx * bx + by * by + bz * bz);
    }
    __syncthreads();

    // ---- inner loop: 1 LDS broadcast read amortized over PPT pairs ----
    #pragma unroll 4
    for (int j = 0; j < cnt; ++j) {
        float4 q = tilebuf[j];
        #pragma unroll
        for (int p = 0; p < PPT; ++p) {
            float t = fmaf(m2x[p], q.x, q.w);
            t = fmaf(m2y[p], q.y, t);
            t = fmaf(m2z[p], q.z, t);
            mn[p] = fminf(mn[p], t);
        }
    }

    // ---- epilogue: add |a|^2, clamp at 0 (matches ref's maximum(d2,0)), atomicMin ----
    #pragma unroll
    for (int p = 0; p < PPT; ++p) {
        int i = base + p * TPB + threadIdx.x;
        if (i < ownCount) {
            float v = fmaxf(mn[p] + aa[p], 0.f);
            atomicMin(&outArr[(size_t)b * ownCount + i], __float_as_uint(v));
        }
    }
}

// B blocks; block b folds batch b: sum(rowmin[n<L])/L + sum(colmin)/M, atomicAdd /B.
__global__ __launch_bounds__(256) void cham_reduce_kernel(
    const unsigned int* __restrict__ rowmin, const unsigned int* __restrict__ colmin,
    const int* __restrict__ lengths, float* __restrict__ out, int B, int N, int M)
{
    __shared__ float wavesum[4];
    const int b    = blockIdx.x;
    const int tid  = threadIdx.x;
    const int lane = tid & 63;
    const int wave = tid >> 6;

    const int L = lengths[b];
    float sx = 0.f, sy = 0.f;
    for (int n = tid; n < L; n += 256) sx += __uint_as_float(rowmin[(size_t)b * N + n]);
    for (int m = tid; m < M; m += 256) sy += __uint_as_float(colmin[(size_t)b * M + m]);
    float v = sx / (float)L + sy / (float)M;
    #pragma unroll
    for (int off = 32; off > 0; off >>= 1) v += __shfl_down(v, off, 64);
    if (lane == 0) wavesum[wave] = v;
    __syncthreads();
    if (tid == 0) {
        float total = wavesum[0] + wavesum[1] + wavesum[2] + wavesum[3];
        atomicAdd(out, total / (float)B);
    }
}

extern "C" void kernel_launch(void* const* d_in, const int* in_sizes, int n_in,
                              void* d_out, int out_size, void* d_ws, size_t ws_size,
                              hipStream_t stream) {
    const float* fg      = (const float*)d_in[0];
    const float* prj     = (const float*)d_in[1];
    const int*   lengths = (const int*)d_in[2];
    float*       out     = (float*)d_out;

    const int B = in_sizes[2];
    const int N = in_sizes[0] / (3 * B);
    const int M = in_sizes[1] / (3 * B);

    unsigned int* rowmin = (unsigned int*)d_ws;
    unsigned int* colmin = rowmin + (size_t)B * N;

    const int totalMins = B * (N + M);
    cham_init_kernel<<<(totalMins + 255) / 256, 256, 0, stream>>>(rowmin, totalMins, out);

    const int tilesX  = (N + OWN_TILE - 1) / OWN_TILE;
    const int chunksX = (M + CHUNK - 1) / CHUNK;
    const int tilesY  = (M + OWN_TILE - 1) / OWN_TILE;
    const int chunksY = (N + CHUNK - 1) / CHUNK;
    const int totalBlocks = B * (tilesX * chunksX + tilesY * chunksY);
    cham_dist_kernel<<<totalBlocks, TPB, 0, stream>>>(
        fg, prj, rowmin, colmin, B, N, M, tilesX, chunksX, tilesY, chunksY);

    cham_reduce_kernel<<<B, 256, 0, stream>>>(rowmin, colmin, lengths, out, B, N, M);
}

// Round 3
// 84.211 us; speedup vs baseline: 3.0045x; 1.0323x over previous
//
#include <hip/hip_runtime.h>

#define TPB 256
#define PPT 8                     // own points per thread
#define WAVE_OWN (64 * PPT)       // 512 contiguous own points per wave
#define OWN_TILE (TPB * PPT)      // 2048 own points per block
#define CHUNK 128                 // other points per block (2KB LDS, staged once)

// Seed min arrays to +inf bits and zero the output accumulator
// (workspace/out are poisoned 0xAA before each timed launch).
__global__ void cham_init_kernel(unsigned int* __restrict__ mins, int count,
                                 float* __restrict__ out) {
    int i = blockIdx.x * blockDim.x + threadIdx.x;
    if (i < count) mins[i] = 0x7F800000u;  // +inf
    if (i == 0) out[0] = 0.f;
}

// side 0 blocks: own = fg rows (N), other = prj (M), out = rowmin
// side 1 blocks: own = prj (M),     other = fg (N),  out = colmin
// d2 = |a|^2 + (|b|^2 - 2 a.b); min the paren term over j, add |a|^2, clamp 0.
// PAD rows (1e4 sentinel) give d2 ~ 3e8 and can never win a min vs any valid
// pair (<= ~100, and L >= 1 guarantees a valid candidate) -> skipping them is
// bitwise identical. Y-side: trim other-range to L. X-side: waves whose own
// range is entirely >= L exit (their rowmin stays +inf, never read).
__global__ __launch_bounds__(TPB) void cham_dist_kernel(
    const float* __restrict__ fg, const float* __restrict__ prj,
    const int* __restrict__ lengths,
    unsigned int* __restrict__ rowmin, unsigned int* __restrict__ colmin,
    int B, int N, int M,
    int tilesX, int chunksX, int tilesY, int chunksY)
{
    const int blocksX = B * tilesX * chunksX;
    int idx = blockIdx.x;
    const int side = (idx >= blocksX) ? 1 : 0;
    if (side) idx -= blocksX;
    const int tilesPer  = side ? tilesY  : tilesX;
    const int chunksPer = side ? chunksY : chunksX;
    const int b     = idx / (tilesPer * chunksPer);
    const int rem   = idx % (tilesPer * chunksPer);
    const int tile  = rem / chunksPer;
    const int chunk = rem % chunksPer;

    const float* own     = side ? prj : fg;
    const float* other   = side ? fg  : prj;
    unsigned int* outArr = side ? colmin : rowmin;
    const int ownCount   = side ? M : N;
    const int otherCount = side ? N : M;
    const int L          = lengths[b];

    const int start = chunk * CHUNK;
    int cnt = min(CHUNK, otherCount - start);
    if (side == 1) {
        if (start >= L) return;          // whole block's others are PAD rows
        cnt = min(cnt, L - start);       // trim straddling chunk
    }

    // ---- stage the other-chunk into LDS (w = |b|^2); single barrier ----
    __shared__ float4 tilebuf[CHUNK];
    if (threadIdx.x < cnt) {
        const float* q = other + ((size_t)b * otherCount + start + threadIdx.x) * 3;
        float bx = q[0], by = q[1], bz = q[2];
        tilebuf[threadIdx.x] = make_float4(bx, by, bz, bx * bx + by * by + bz * bz);
    }
    __syncthreads();

    // ---- per-wave contiguous own range; exit padded waves (no barrier after) ----
    const int lane  = threadIdx.x & 63;
    const int wave  = threadIdx.x >> 6;
    const int wbase = tile * OWN_TILE + wave * WAVE_OWN;
    if (wbase >= ownCount) return;
    if (side == 0 && wbase >= L) return;  // own rows all PAD: rowmin never read

    float m2x[PPT], m2y[PPT], m2z[PPT], aa[PPT], mn[PPT];
    #pragma unroll
    for (int p = 0; p < PPT; ++p) {
        int i  = wbase + p * 64 + lane;
        int li = min(i, ownCount - 1);   // clamped load; store guarded later
        const float* a = own + ((size_t)b * ownCount + li) * 3;
        float ax = a[0], ay = a[1], az = a[2];
        m2x[p] = -2.f * ax; m2y[p] = -2.f * ay; m2z[p] = -2.f * az;
        aa[p]  = ax * ax + ay * ay + az * az;
        mn[p]  = __int_as_float(0x7F800000);
    }

    // ---- inner loop: 2 LDS broadcast reads amortized over 2*PPT pairs, min3 ----
    int j = 0;
    #pragma unroll 2
    for (; j + 1 < cnt; j += 2) {
        float4 q0 = tilebuf[j];
        float4 q1 = tilebuf[j + 1];
        #pragma unroll
        for (int p = 0; p < PPT; ++p) {
            float t0 = fmaf(m2x[p], q0.x, q0.w);
            t0 = fmaf(m2y[p], q0.y, t0);
            t0 = fmaf(m2z[p], q0.z, t0);
            float t1 = fmaf(m2x[p], q1.x, q1.w);
            t1 = fmaf(m2y[p], q1.y, t1);
            t1 = fmaf(m2z[p], q1.z, t1);
            mn[p] = fminf(fminf(t0, t1), mn[p]);   // -> v_min3_f32
        }
    }
    if (j < cnt) {                                  // odd tail (trimmed chunks)
        float4 q0 = tilebuf[j];
        #pragma unroll
        for (int p = 0; p < PPT; ++p) {
            float t0 = fmaf(m2x[p], q0.x, q0.w);
            t0 = fmaf(m2y[p], q0.y, t0);
            t0 = fmaf(m2z[p], q0.z, t0);
            mn[p] = fminf(mn[p], t0);
        }
    }

    // ---- epilogue: add |a|^2, clamp 0 (ref's maximum(d2,0)), atomicMin ----
    #pragma unroll
    for (int p = 0; p < PPT; ++p) {
        int i = wbase + p * 64 + lane;
        if (i < ownCount) {
            float v = fmaxf(mn[p] + aa[p], 0.f);
            atomicMin(&outArr[(size_t)b * ownCount + i], __float_as_uint(v));
        }
    }
}

// B blocks; block b folds batch b: sum(rowmin[n<L])/L + sum(colmin)/M, atomicAdd /B.
__global__ __launch_bounds__(256) void cham_reduce_kernel(
    const unsigned int* __restrict__ rowmin, const unsigned int* __restrict__ colmin,
    const int* __restrict__ lengths, float* __restrict__ out, int B, int N, int M)
{
    __shared__ float wavesum[4];
    const int b    = blockIdx.x;
    const int tid  = threadIdx.x;
    const int lane = tid & 63;
    const int wave = tid >> 6;

    const int L = lengths[b];
    float sx = 0.f, sy = 0.f;
    for (int n = tid; n < L; n += 256) sx += __uint_as_float(rowmin[(size_t)b * N + n]);
    for (int m = tid; m < M; m += 256) sy += __uint_as_float(colmin[(size_t)b * M + m]);
    float v = sx / (float)L + sy / (float)M;
    #pragma unroll
    for (int off = 32; off > 0; off >>= 1) v += __shfl_down(v, off, 64);
    if (lane == 0) wavesum[wave] = v;
    __syncthreads();
    if (tid == 0) {
        float total = wavesum[0] + wavesum[1] + wavesum[2] + wavesum[3];
        atomicAdd(out, total / (float)B);
    }
}

extern "C" void kernel_launch(void* const* d_in, const int* in_sizes, int n_in,
                              void* d_out, int out_size, void* d_ws, size_t ws_size,
                              hipStream_t stream) {
    const float* fg      = (const float*)d_in[0];
    const float* prj     = (const float*)d_in[1];
    const int*   lengths = (const int*)d_in[2];
    float*       out     = (float*)d_out;

    const int B = in_sizes[2];
    const int N = in_sizes[0] / (3 * B);
    const int M = in_sizes[1] / (3 * B);

    unsigned int* rowmin = (unsigned int*)d_ws;
    unsigned int* colmin = rowmin + (size_t)B * N;

    const int totalMins = B * (N + M);
    cham_init_kernel<<<(totalMins + 255) / 256, 256, 0, stream>>>(rowmin, totalMins, out);

    const int tilesX  = (N + OWN_TILE - 1) / OWN_TILE;
    const int chunksX = (M + CHUNK - 1) / CHUNK;
    const int tilesY  = (M + OWN_TILE - 1) / OWN_TILE;
    const int chunksY = (N + CHUNK - 1) / CHUNK;
    const int totalBlocks = B * (tilesX * chunksX + tilesY * chunksY);
    cham_dist_kernel<<<totalBlocks, TPB, 0, stream>>>(
        fg, prj, lengths, rowmin, colmin, B, N, M, tilesX, chunksX, tilesY, chunksY);

    cham_reduce_kernel<<<B, 256, 0, stream>>>(rowmin, colmin, lengths, out, B, N, M);
}